// Round 7
// baseline (146.035 us; speedup 1.0000x reference)
//
#include <hip/hip_runtime.h>

// LogSig rolling: B=256, NT=4096, D=12, KERNEL=64, STRIDE=16 -> W=253, 78 outs/window.
// Chen's-relation fused kernel: one block per batch (grid=256, 512 threads).
//
// Phase 1a: thread t streams rows 8t..8t+8 (clamped at 4095) computing the
//   8-delta sub-signature: d_k = x_{k+1}-x_k, wedge acc += c ^ d, c += d.
//   After the loop c = inc8 (x_end-x_start), d = trailing delta.
//   Streaming + 3-row lookahead keeps ~150 VGPRs live (round-6 post-mortem:
//   VGPR_Count=128 forced spills -> 3x WRITE_SIZE + 65us latency-bound).
//   amdgpu_waves_per_eu(2,2) pins the allocator at the 256-reg / 2-wave point
//   that the 94KB dynamic LDS already caps us to (8 waves/CU).
// Phase 1b: lane-pair Chen combine via __shfl_xor(.,1) -> 16-delta sub
//   S16[t>>1]: acc = aL + aR + IL^IR ; inc = IL + IR. Even lanes store to LDS
//   (stride 79). Odd lanes store their trailing delta to the dl table
//   (stride 13): window w's trailing delta lives in thread 2w+7 -> slot w+3;
//   t=511's clamp zeroes slot 255 = window 252's dl.
// Phase 2: thread w < 253 left-folds S16[w..w+3] by Chen (64 deltas), removes
//   the trailing delta: I_Q = I - dl ; acc_Q = acc - I_Q ^ dl.
// Output: vals staged to LDS (overwriting the dead sig region after a
//   barrier), then block-wide coalesced float2 copy (round-6 stores were
//   64-scattered-lines per instruction).

namespace {
constexpr int kB = 256;
constexpr int kNT = 4096;
constexpr int kD = 12;
constexpr int kW = 253;
constexpr int kNPair = 66;
constexpr int kOutC = 78;                 // 12 + 66
constexpr int kThreads = 512;
constexpr int kSub = 256;                 // 16-delta subs per batch
constexpr int kSigStride = 79;            // 78 + 1 pad; odd -> conflict-free reads
constexpr int kDlStride = 13;             // 12 + 1 pad
constexpr int kDlBase = kSub * kSigStride;                 // 20224 floats
constexpr int kLdsFloats = kDlBase + kSub * kDlStride;     // 23552 floats
constexpr size_t kLdsBytes = (size_t)kLdsFloats * sizeof(float);  // 94208 B
constexpr int kOutFloats = kW * kOutC;    // 19734 (fits in sig region: < 20224)
constexpr int kOutF2 = kOutFloats / 2;    // 9867
}

__device__ __forceinline__ void load_row(const float* __restrict__ p, float r[kD]) {
    // rows are 48B, 16B-aligned ((b*4096+t)*12*4 % 16 == 0) -> 3x float4
    float4 a = *reinterpret_cast<const float4*>(p);
    float4 b = *reinterpret_cast<const float4*>(p + 4);
    float4 c = *reinterpret_cast<const float4*>(p + 8);
    r[0] = a.x; r[1] = a.y; r[2]  = a.z; r[3]  = a.w;
    r[4] = b.x; r[5] = b.y; r[6]  = b.z; r[7]  = b.w;
    r[8] = c.x; r[9] = c.y; r[10] = c.z; r[11] = c.w;
}

__global__ __launch_bounds__(kThreads)
__attribute__((amdgpu_waves_per_eu(2, 2)))
void logsig_chen16(const float* __restrict__ inp, float* __restrict__ out) {
    extern __shared__ float lds[];
    const int b = blockIdx.x;
    const int t = threadIdx.x;
    const float* bb = inp + (size_t)b * kNT * kD;

    // ---------------- Phase 1a: streamed 8-delta sub-signature ----------------
    float R[9][kD];                        // SSA-split by unroll; ~4 rows live
    {
        int g0 = 8 * t;
        load_row(bb + (size_t)(g0 > kNT - 1 ? kNT - 1 : g0) * kD, R[0]);
        int g1 = 8 * t + 1;
        load_row(bb + (size_t)(g1 > kNT - 1 ? kNT - 1 : g1) * kD, R[1]);
        int g2 = 8 * t + 2;
        load_row(bb + (size_t)(g2 > kNT - 1 ? kNT - 1 : g2) * kD, R[2]);
    }
    float c[kD], d[kD], acc8[kNPair];
#pragma unroll
    for (int p = 0; p < kNPair; ++p) acc8[p] = 0.f;
#pragma unroll
    for (int k = 0; k < 8; ++k) {
        if (k < 6) {                       // prefetch row k+3 (3 ahead of use)
            int gr = 8 * t + k + 3;
            gr = gr > kNT - 1 ? kNT - 1 : gr;   // only t=511 clamps -> d7=0
            load_row(bb + (size_t)gr * kD, R[k + 3]);
        }
#pragma unroll
        for (int i = 0; i < kD; ++i) d[i] = R[k + 1][i] - R[k][i];
        if (k > 0) {                       // k=0 has c==0 -> no wedge
            int p = 0;
#pragma unroll
            for (int i = 0; i < kD; ++i) {
#pragma unroll
                for (int j = i + 1; j < kD; ++j) {
                    acc8[p] = fmaf(c[i], d[j], fmaf(-c[j], d[i], acc8[p]));
                    ++p;
                }
            }
        }
#pragma unroll
        for (int i = 0; i < kD; ++i) c[i] = (k == 0) ? d[i] : c[i] + d[i];
    }
    // c = inc8 = x8 - x0 ; d = trailing delta x8 - x7

    // ---------------- Phase 1b: pair Chen -> 16-delta sub + dl table ----------------
    const int odd = t & 1;
    if (odd) {                             // publish trailing 1-delta
        float* dd = lds + kDlBase + (size_t)(t >> 1) * kDlStride;
#pragma unroll
        for (int i = 0; i < kD; ++i) dd[i] = d[i];
    }
    float IL[kD], IR[kD];
#pragma unroll
    for (int i = 0; i < kD; ++i) {
        float o = __shfl_xor(c[i], 1);
        IL[i] = odd ? o : c[i];
        IR[i] = odd ? c[i] : o;
    }
    float* dst = lds + (size_t)(t >> 1) * kSigStride;
    if (!odd) {
#pragma unroll
        for (int i = 0; i < kD; ++i) dst[i] = IL[i] + IR[i];
    }
    {
        int p = 0;
#pragma unroll
        for (int i = 0; i < kD; ++i) {
#pragma unroll
            for (int j = i + 1; j < kD; ++j) {
                float oa = __shfl_xor(acc8[p], 1);
                float aL = odd ? oa : acc8[p];
                float aR = odd ? acc8[p] : oa;
                float v = fmaf(IL[i], IR[j], fmaf(-IL[j], IR[i], aL + aR));
                if (!odd) dst[kD + p] = v;   // exec-masked store
                ++p;
            }
        }
    }

    __syncthreads();

    // ---------------- Phase 2: fold 4 subs per window + tail removal ----------------
    float vals[kOutC];
    const bool active = (t < kW);
    if (active) {
        const int w = t;
        float I[kD], acc[kNPair];
        {   // init from sub w
            const float* src = lds + (size_t)w * kSigStride;
#pragma unroll
            for (int i = 0; i < kD; ++i) I[i] = src[i];
#pragma unroll
            for (int p = 0; p < kNPair; ++p) acc[p] = src[kD + p];
        }
#pragma unroll
        for (int r = 1; r < 4; ++r) {
            const float* src = lds + (size_t)(w + r) * kSigStride;
            float J[kOutC];
#pragma unroll
            for (int q = 0; q < kOutC; ++q) J[q] = src[q];
            int p = 0;
#pragma unroll
            for (int i = 0; i < kD; ++i) {
#pragma unroll
                for (int j = i + 1; j < kD; ++j) {
                    float a = acc[p] + J[kD + p];          // accL + accR
                    a = fmaf(I[i], J[j], a);               // + IL_i * IR_j
                    a = fmaf(-I[j], J[i], a);              // - IL_j * IR_i
                    acc[p] = a;
                    ++p;
                }
            }
#pragma unroll
            for (int i = 0; i < kD; ++i) I[i] += J[i];     // after cross term
        }

        float dl[kD];                      // trailing delta (thread 2w+7 -> slot w+3)
        {
            const float* dd = lds + kDlBase + (size_t)(w + 3) * kDlStride;
#pragma unroll
            for (int i = 0; i < kD; ++i) dl[i] = dd[i];
        }
#pragma unroll
        for (int i = 0; i < kD; ++i) vals[i] = I[i] - dl[i];   // lvl1 = x63 - x0
        {
            int p = 0;
#pragma unroll
            for (int i = 0; i < kD; ++i) {
#pragma unroll
                for (int j = i + 1; j < kD; ++j) {
                    float a = acc[p];
                    a = fmaf(-vals[i], dl[j], a);
                    a = fmaf(vals[j], dl[i], a);
                    vals[kD + p] = 0.5f * a;
                    ++p;
                }
            }
        }
    }

    __syncthreads();                       // all sig/dl reads complete

    if (active) {                          // stage vals into dead sig region
        float* vdst = lds + (size_t)t * kOutC;
#pragma unroll
        for (int q = 0; q < kOutC; ++q) vdst[q] = vals[q];
    }

    __syncthreads();

    // coalesced block output: 9867 float2, consecutive lanes -> consecutive 8B
    const float2* s2 = reinterpret_cast<const float2*>(lds);
    float2* o2 = reinterpret_cast<float2*>(out + (size_t)b * kOutFloats);
    for (int idx = t; idx < kOutF2; idx += kThreads)
        o2[idx] = s2[idx];
}

extern "C" void kernel_launch(void* const* d_in, const int* in_sizes, int n_in,
                              void* d_out, int out_size, void* d_ws, size_t ws_size,
                              hipStream_t stream) {
    const float* inp = (const float*)d_in[0];
    float* out = (float*)d_out;
    // >64KB dynamic LDS: declare cap every call (idempotent, not stream-ordered,
    // graph-capture-safe; no static guards per harness rules)
    (void)hipFuncSetAttribute((const void*)logsig_chen16,
                              hipFuncAttributeMaxDynamicSharedMemorySize,
                              (int)kLdsBytes);
    logsig_chen16<<<kB, kThreads, kLdsBytes, stream>>>(inp, out);
}